// Round 1
// baseline (258.968 us; speedup 1.0000x reference)
//
#include <hip/hip_runtime.h>

#define DIN 128
#define DH 64
#define DOUT 32
#define BN_EPS 1e-5f

#define BK 128          // nodes per bucket
#define BKSH 7          // log2(BK)
#define NBK_MAX 784     // ceil(100000/128)=782, padded
#define G 256           // counting-sort partition blocks; 32/XCD open-line set ~3.2MB fits L2
#define CAP 2560        // fixed per-bucket region capacity (mean 2048, +11 sigma)
#define CCAP 3584       // col region capacity: CAP + 128 nodes * 7 max pad (pad-to-8 sentinel)

typedef __attribute__((ext_vector_type(8))) short short8;
typedef __attribute__((ext_vector_type(4))) float floatx4;

// bf16 helpers (RNE store, exact load)
__device__ __forceinline__ unsigned short f2bf(float f) {
    union { float f; unsigned u; } v; v.f = f;
    unsigned r = (v.u + 0x7FFFu + ((v.u >> 16) & 1u)) >> 16;
    return (unsigned short)r;
}
__device__ __forceinline__ float bf2f(unsigned short h) {
    union { unsigned u; float f; } v; v.u = ((unsigned)h) << 16;
    return v.f;
}
__device__ __forceinline__ float lo_f(unsigned u) {
    union { unsigned u; float f; } v; v.u = u << 16;
    return v.f;
}
__device__ __forceinline__ float hi_f(unsigned u) {
    union { unsigned u; float f; } v; v.u = u & 0xFFFF0000u;
    return v.f;
}
__device__ __forceinline__ unsigned pack2bf(float lo, float hi) {
    return (unsigned)f2bf(lo) | ((unsigned)f2bf(hi) << 16);
}

// ---------------- counting sort pass 1: per-block bucket histogram (g-major write) ----------------

__global__ __launch_bounds__(512) void hist_k(const int* __restrict__ dst, int* __restrict__ hist_g,
                                              int E, int nbk, int chunk) {
    __shared__ int hist[NBK_MAX];
    int g = blockIdx.x, tid = threadIdx.x;
    for (int b = tid; b < nbk; b += 512) hist[b] = 0;
    __syncthreads();
    int i0 = g * chunk, iend = min(i0 + chunk, E);
    for (int i = i0 + tid; i < iend; i += 512)
        atomicAdd(&hist[dst[i] >> BKSH], 1);
    __syncthreads();
    for (int b = tid; b < nbk; b += 512)
        hist_g[(size_t)g * nbk + b] = hist[b];   // coalesced row write
}

// ---------------- pass 2: per-bucket exclusive scan over the G=256 block-counts ----------------

__global__ __launch_bounds__(256) void scan_k(const int* __restrict__ hist_g, int* __restrict__ rowoff,
                                              int* __restrict__ tot, int nbk) {
    __shared__ int seg[16][17];
    int tid = threadIdx.x;
    int gl = tid >> 4, bl = tid & 15;
    int b = blockIdx.x * 16 + bl;
    bool bok = b < nbk;
    int vals[16];
    int psum = 0;
    #pragma unroll
    for (int j = 0; j < 16; j++) {
        int g = gl * 16 + j;
        int v = bok ? hist_g[(size_t)g * nbk + b] : 0;   // 16 independent loads in flight
        vals[j] = v; psum += v;
    }
    seg[gl][bl] = psum;
    __syncthreads();
    #pragma unroll
    for (int off = 1; off < 16; off <<= 1) {
        int t = (gl >= off) ? seg[gl - off][bl] : 0;
        __syncthreads();
        seg[gl][bl] += t;
        __syncthreads();
    }
    int run = seg[gl][bl] - psum;                        // exclusive base of this 16-g segment
    if (gl == 15 && bok) tot[b] = seg[15][bl];
    #pragma unroll
    for (int j = 0; j < 16; j++) {
        int g = gl * 16 + j;
        if (bok) rowoff[(size_t)g * nbk + b] = run;      // g-major: scatter_k reads rows coalesced
        run += vals[j];
    }
}

// ---------------- pass 3: scatter records into fixed-CAP bucket regions (no global atomics) ----------------

__global__ __launch_bounds__(512) void scatter_k(const int* __restrict__ src, const int* __restrict__ dst,
                                                 const int* __restrict__ rowoff,
                                                 unsigned* __restrict__ recs, int E, int nbk, int chunk) {
    __shared__ int cur[NBK_MAX];
    int g = blockIdx.x, tid = threadIdx.x;
    for (int b = tid; b < nbk; b += 512)
        cur[b] = b * CAP + rowoff[(size_t)g * nbk + b];   // coalesced row read (g-major)
    __syncthreads();
    int i0 = g * chunk, iend = min(i0 + chunk, E);
    for (int i = i0 + tid; i < iend; i += 512) {
        int s = src[i], d = dst[i];
        int b = d >> BKSH;
        int slot = atomicAdd(&cur[b], 1);   // LDS atomic
        if (slot < (b + 1) * CAP)           // overflow guard (never fires at CAP=mean+11sigma)
            recs[slot] = ((unsigned)s << BKSH) | (unsigned)(d & (BK - 1));
    }
}

// ---------------- pass 4: within-bucket node sort -> CSR (pad-to-8, sentinel n), wave-private cursors ----------------
// 8 waves: wave w owns slice e = lo + w*64 + lane (step 512). deg8[w][dl] private histogram;
// wb[w][dl] = bas[dl] + prefix of waves <w, used directly as the wave's private scatter cursor.
// Adjacency lists are padded to a multiple of 8 with sentinel column n (an all-zero feature row)
// so the agg kernels run a branchless loop with no predicated tail.

__global__ __launch_bounds__(512) void csr_k(const unsigned* __restrict__ recs, const int* __restrict__ tot,
                                             float* __restrict__ dis, int2* __restrict__ rpde,
                                             int* __restrict__ col, int n) {
    __shared__ int deg8[8][BK];   // 4 KB
    __shared__ int wb[8][BK];     // 4 KB
    __shared__ int deg[BK], sc[BK], bas[BK];
    int b = blockIdx.x, tid = threadIdx.x;
    int w = tid >> 6, lane = tid & 63;
    for (int i = tid; i < 8 * BK; i += 512) ((int*)deg8)[i] = 0;
    __syncthreads();
    int lo = b * CAP;            // recs region (stride CAP)
    int clo = b * CCAP;          // col region (stride CCAP, has room for padding)
    int ne = min(tot[b], CAP);
    int hi = lo + ne;
    for (int e = lo + w * 64 + lane; e < hi; e += 512)
        atomicAdd(&deg8[w][recs[e] & (BK - 1)], 1);
    __syncthreads();
    if (tid < BK) {
        int run = 0;
        #pragma unroll
        for (int ww = 0; ww < 8; ww++) { wb[ww][tid] = run; run += deg8[ww][tid]; }
        deg[tid] = run;
        sc[tid] = (run + 7) & ~7;                 // scan over PADDED degree
    }
    __syncthreads();
    for (int off = 1; off < BK; off <<= 1) {
        int t = (tid < BK && tid >= off) ? sc[tid - off] : 0;
        __syncthreads();
        if (tid < BK) sc[tid] += t;
        __syncthreads();
    }
    if (tid < BK) {
        int d = deg[tid];
        int pdeg = (d + 7) & ~7;
        int base = sc[tid] - pdeg;
        bas[tid] = base;
        int g = b * BK + tid;
        if (g < n) {
            dis[g] = rsqrtf((float)(d + 1));      // +1 self-loop
            rpde[g] = make_int2(clo + base, d);
        }
        for (int j = d; j < pdeg; j++)            // sentinel padding (<=7 per node)
            col[clo + base + j] = n;
    }
    __syncthreads();
    for (int i = tid; i < 8 * BK; i += 512)
        ((int*)wb)[i] += bas[i & (BK - 1)];       // wb[w][dl] += bas[dl]
    __syncthreads();
    for (int e = lo + w * 64 + lane; e < hi; e += 512) {
        unsigned r = recs[e];
        int dl = r & (BK - 1);
        int k = atomicAdd(&wb[w][dl], 1);         // wave-private cursor
        col[clo + k] = (int)(r >> BKSH);
    }
}

// ---------------- GEMM1 (MFMA bf16): h1s = bf16((x @ W1) * dis[row]); row n = zero sentinel ----------------

__global__ __launch_bounds__(256) void gemm1_k(const float* __restrict__ x,
                                               const float* __restrict__ W1,
                                               const float* __restrict__ dis,
                                               unsigned short* __restrict__ h1s, int n) {
    __shared__ unsigned short xb[64][136];   // +8 pad: rows 272B apart -> 2-way bank alias (free)
    __shared__ unsigned short wt[64][136];
    int tid = threadIdx.x;
    int r0b = blockIdx.x * 64;

    for (int c = tid; c < 2048; c += 256) {
        int k = c >> 4, n4 = (c & 15) * 4;
        float4 v = ((const float4*)W1)[c];
        wt[n4 + 0][k] = f2bf(v.x);
        wt[n4 + 1][k] = f2bf(v.y);
        wt[n4 + 2][k] = f2bf(v.z);
        wt[n4 + 3][k] = f2bf(v.w);
    }
    for (int c = tid; c < 2048; c += 256) {
        int r = c >> 5, k4 = (c & 31) * 4;
        int gr = r0b + r;
        float4 v = make_float4(0.f, 0.f, 0.f, 0.f);
        if (gr < n) v = ((const float4*)x)[(gr << 5) + (k4 >> 2)];
        ushort4 o;
        o.x = f2bf(v.x); o.y = f2bf(v.y); o.z = f2bf(v.z); o.w = f2bf(v.w);
        *(ushort4*)&xb[r][k4] = o;
    }
    __syncthreads();

    int w = tid >> 6, lane = tid & 63;
    int rr = lane & 15, q = lane >> 4;
    floatx4 acc0 = {0.f, 0.f, 0.f, 0.f}, acc1 = acc0, acc2 = acc0, acc3 = acc0;
    #pragma unroll
    for (int kt = 0; kt < 4; kt++) {
        int k0 = kt * 32 + q * 8;
        short8 a  = *(const short8*)&xb[w * 16 + rr][k0];
        short8 b0 = *(const short8*)&wt[rr][k0];
        short8 b1 = *(const short8*)&wt[16 + rr][k0];
        short8 b2 = *(const short8*)&wt[32 + rr][k0];
        short8 b3 = *(const short8*)&wt[48 + rr][k0];
        acc0 = __builtin_amdgcn_mfma_f32_16x16x32_bf16(a, b0, acc0, 0, 0, 0);
        acc1 = __builtin_amdgcn_mfma_f32_16x16x32_bf16(a, b1, acc1, 0, 0, 0);
        acc2 = __builtin_amdgcn_mfma_f32_16x16x32_bf16(a, b2, acc2, 0, 0, 0);
        acc3 = __builtin_amdgcn_mfma_f32_16x16x32_bf16(a, b3, acc3, 0, 0, 0);
    }
    #pragma unroll
    for (int t = 0; t < 4; t++) {
        int gr = r0b + w * 16 + q * 4 + t;
        if (gr < n) {
            float dd = dis[gr];
            unsigned short* o = &h1s[gr * 64];
            o[rr]      = f2bf(acc0[t] * dd);
            o[16 + rr] = f2bf(acc1[t] * dd);
            o[32 + rr] = f2bf(acc2[t] * dd);
            o[48 + rr] = f2bf(acc3[t] * dd);
        } else if (gr == n) {                    // sentinel zero row for padded gathers
            unsigned short* o = &h1s[gr * 64];
            o[rr] = 0; o[16 + rr] = 0; o[32 + rr] = 0; o[48 + rr] = 0;
        }
    }
}

// ---------------- Aggregation layer 1: wave per node, dwordx2 gathers (4 feats/lane, 4 edges/instr) ----------------
// col padded to multiple of 8 with sentinel n (zero row) -> branchless loop, no tail predication.
// lane = eslot*16 + f2: f2 indexes the 16 uint2 of a 64-feat bf16 row; eslot in [0,4) covers 8 edges
// per iteration via two gathers. Guarded col prefetch pipelines the col->gather dependency.

__global__ __launch_bounds__(256) void agg1_k(const unsigned* __restrict__ h1p,
                                              const int2* __restrict__ rpde,
                                              const int* __restrict__ col,
                                              unsigned* __restrict__ outp, int n) {
    int node = (blockIdx.x * 256 + threadIdx.x) >> 6;
    int lane = threadIdx.x & 63;
    if (node >= n) return;
    int f2 = lane & 15, eslot = lane >> 4;
    int2 rd = rpde[node];
    int e  = __builtin_amdgcn_readfirstlane(rd.x);
    int dg = __builtin_amdgcn_readfirstlane(rd.y);
    int pdg = (dg + 7) & ~7;

    const uint2* h1q = (const uint2*)h1p;        // 16 uint2 per row
    float l0x = 0.f, h0x = 0.f, l0y = 0.f, h0y = 0.f;
    float l1x = 0.f, h1x = 0.f, l1y = 0.f, h1y = 0.f;
    int c0 = n, c1 = n;
    if (pdg > 0) { c0 = col[e + eslot]; c1 = col[e + 4 + eslot]; }
    for (int b = 0; b < pdg; b += 8) {
        uint2 u0 = h1q[c0 * 16 + f2];
        uint2 u1 = h1q[c1 * 16 + f2];
        int bn = (b + 8 < pdg) ? b + 8 : b;      // guarded prefetch (last iter re-reads, harmless)
        c0 = col[e + bn + eslot];
        c1 = col[e + bn + 4 + eslot];
        l0x += lo_f(u0.x); h0x += hi_f(u0.x);
        l0y += lo_f(u0.y); h0y += hi_f(u0.y);
        l1x += lo_f(u1.x); h1x += hi_f(u1.x);
        l1y += lo_f(u1.y); h1y += hi_f(u1.y);
    }
    float ax = l0x + l1x, bx = h0x + h1x;
    float ay = l0y + l1y, by = h0y + h1y;
    ax += __shfl_xor(ax, 16, 64); ax += __shfl_xor(ax, 32, 64);
    bx += __shfl_xor(bx, 16, 64); bx += __shfl_xor(bx, 32, 64);
    ay += __shfl_xor(ay, 16, 64); ay += __shfl_xor(ay, 32, 64);
    by += __shfl_xor(by, 16, 64); by += __shfl_xor(by, 32, 64);
    if (eslot == 0) {
        uint2 us = h1q[node * 16 + f2];
        float dn = rsqrtf((float)(dg + 1));
        uint2 o;
        o.x = pack2bf((ax + lo_f(us.x)) * dn, (bx + hi_f(us.x)) * dn);
        o.y = pack2bf((ay + lo_f(us.y)) * dn, (by + hi_f(us.y)) * dn);
        ((uint2*)outp)[node * 16 + f2] = o;
    }
}

// ---------------- BN stats (bf16 input) ----------------

__global__ __launch_bounds__(256) void bnstats_k(const unsigned short* __restrict__ agg1b,
                                                 float* __restrict__ stats, int n) {
    int f = threadIdx.x & 63, g = threadIdx.x >> 6;
    float sum = 0.f, sq = 0.f;
    for (int r = blockIdx.x * 4 + g; r < n; r += gridDim.x * 4) {
        float v = bf2f(agg1b[r * 64 + f]);
        sum += v; sq += v * v;
    }
    __shared__ float s1[4][64], s2[4][64];
    s1[g][f] = sum; s2[g][f] = sq;
    __syncthreads();
    if (g == 0) {
        sum = s1[0][f] + s1[1][f] + s1[2][f] + s1[3][f];
        sq  = s2[0][f] + s2[1][f] + s2[2][f] + s2[3][f];
        atomicAdd(&stats[f], sum);
        atomicAdd(&stats[64 + f], sq);
    }
}

// ---------------- GEMM2 (MFMA bf16), BN fold inlined: h2s = bf16((relu(agg1b*s+t) @ W2) * dis[row]) ----------------

__global__ __launch_bounds__(256) void gemm2_k(const unsigned short* __restrict__ agg1b,
                                               const float* __restrict__ W2,
                                               const float* __restrict__ stats,
                                               const float* __restrict__ gamma, const float* __restrict__ beta,
                                               const float* __restrict__ dis,
                                               unsigned short* __restrict__ h2s, float invn, int n) {
    __shared__ unsigned short ab[64][72];    // +8 pad
    __shared__ unsigned short wt[32][72];
    __shared__ float s_s[64], s_t[64];
    int tid = threadIdx.x;
    int r0b = blockIdx.x * 64;
    if (tid < 64) {                          // BN fold (b1 cancels by shift invariance)
        float mean = stats[tid] * invn;
        float var = stats[64 + tid] * invn - mean * mean;
        float s = gamma[tid] * rsqrtf(var + BN_EPS);
        s_s[tid] = s;
        s_t[tid] = beta[tid] - mean * s;
    }
    for (int c = tid; c < 512; c += 256) {   // stage W2^T (512 float4)
        int k = c >> 3, n4 = (c & 7) * 4;
        float4 v = ((const float4*)W2)[c];
        wt[n4 + 0][k] = f2bf(v.x);
        wt[n4 + 1][k] = f2bf(v.y);
        wt[n4 + 2][k] = f2bf(v.z);
        wt[n4 + 3][k] = f2bf(v.w);
    }
    __syncthreads();
    for (int c = tid; c < 512; c += 256) {
        int r = c >> 3, k0 = (c & 7) * 8;
        int gr = r0b + r;
        unsigned short tmp[8];
        if (gr < n) {
            const unsigned short* ap = &agg1b[gr * 64 + k0];
            #pragma unroll
            for (int j = 0; j < 8; j++)
                tmp[j] = f2bf(fmaxf(bf2f(ap[j]) * s_s[k0 + j] + s_t[k0 + j], 0.f));
        } else {
            #pragma unroll
            for (int j = 0; j < 8; j++) tmp[j] = 0;
        }
        *(short8*)&ab[r][k0] = *(short8*)tmp;
    }
    __syncthreads();

    int w = tid >> 6, lane = tid & 63;
    int rr = lane & 15, q = lane >> 4;
    floatx4 acc0 = {0.f, 0.f, 0.f, 0.f}, acc1 = acc0;
    #pragma unroll
    for (int kt = 0; kt < 2; kt++) {
        int k0 = kt * 32 + q * 8;
        short8 a  = *(const short8*)&ab[w * 16 + rr][k0];
        short8 b0 = *(const short8*)&wt[rr][k0];
        short8 b1 = *(const short8*)&wt[16 + rr][k0];
        acc0 = __builtin_amdgcn_mfma_f32_16x16x32_bf16(a, b0, acc0, 0, 0, 0);
        acc1 = __builtin_amdgcn_mfma_f32_16x16x32_bf16(a, b1, acc1, 0, 0, 0);
    }
    #pragma unroll
    for (int t = 0; t < 4; t++) {
        int gr = r0b + w * 16 + q * 4 + t;
        if (gr < n) {
            float dd = dis[gr];
            h2s[gr * 32 + rr]      = f2bf(acc0[t] * dd);
            h2s[gr * 32 + 16 + rr] = f2bf(acc1[t] * dd);
        } else if (gr == n) {                // sentinel zero row for padded gathers
            h2s[gr * 32 + rr]      = 0;
            h2s[gr * 32 + 16 + rr] = 0;
        }
    }
}

// ---------------- Aggregation layer 2: node per half-wave, dwordx2 gathers (4 feats/lane, 4 edges/instr) ----------------

__global__ __launch_bounds__(256) void agg2_k(const unsigned* __restrict__ h2p,
                                              const int2* __restrict__ rpde,
                                              const int* __restrict__ col, const float* __restrict__ b2,
                                              float* __restrict__ out, int n) {
    int wave = (blockIdx.x * 256 + threadIdx.x) >> 6;
    int lane = threadIdx.x & 63;
    int half = lane >> 5, hl = lane & 31;
    int node = wave * 2 + half;
    if (node >= n) return;
    int f2 = hl & 7, eslot = hl >> 3;        // uint2 column of 8-uint2 row; eslot in [0,4)
    int2 rd = rpde[node];                    // uniform within half
    int e = rd.x, dg = rd.y;
    int pdg = (dg + 7) & ~7;

    const uint2* h2q = (const uint2*)h2p;    // 8 uint2 per row
    float l0x = 0.f, h0x = 0.f, l0y = 0.f, h0y = 0.f;
    float l1x = 0.f, h1x = 0.f, l1y = 0.f, h1y = 0.f;
    int c0 = n, c1 = n;
    if (pdg > 0) { c0 = col[e + eslot]; c1 = col[e + 4 + eslot]; }
    for (int b = 0; b < pdg; b += 8) {
        uint2 u0 = h2q[c0 * 8 + f2];
        uint2 u1 = h2q[c1 * 8 + f2];
        int bn = (b + 8 < pdg) ? b + 8 : b;  // guarded prefetch
        c0 = col[e + bn + eslot];
        c1 = col[e + bn + 4 + eslot];
        l0x += lo_f(u0.x); h0x += hi_f(u0.x);
        l0y += lo_f(u0.y); h0y += hi_f(u0.y);
        l1x += lo_f(u1.x); h1x += hi_f(u1.x);
        l1y += lo_f(u1.y); h1y += hi_f(u1.y);
    }
    float ax = l0x + l1x, bx = h0x + h1x;
    float ay = l0y + l1y, by = h0y + h1y;
    ax += __shfl_xor(ax, 8, 64); ax += __shfl_xor(ax, 16, 64);
    bx += __shfl_xor(bx, 8, 64); bx += __shfl_xor(bx, 16, 64);
    ay += __shfl_xor(ay, 8, 64); ay += __shfl_xor(ay, 16, 64);
    by += __shfl_xor(by, 8, 64); by += __shfl_xor(by, 16, 64);
    if (eslot == 0) {
        uint2 us = h2q[node * 8 + f2];
        float dn = rsqrtf((float)(dg + 1));
        float4 bb = ((const float4*)b2)[f2];
        float4 o;
        o.x = (ax + lo_f(us.x)) * dn + bb.x;
        o.y = (bx + hi_f(us.x)) * dn + bb.y;
        o.z = (ay + lo_f(us.y)) * dn + bb.z;
        o.w = (by + hi_f(us.y)) * dn + bb.w;
        ((float4*)out)[node * 8 + f2] = o;
    }
}

// ---------------- launch ----------------

extern "C" void kernel_launch(void* const* d_in, const int* in_sizes, int n_in,
                              void* d_out, int out_size, void* d_ws, size_t ws_size,
                              hipStream_t stream) {
    const float* x      = (const float*)d_in[0];
    const int*   ei     = (const int*)d_in[1];
    const float* W1     = (const float*)d_in[2];
    // d_in[3] = b1 (cancels inside BN)
    const float* gamma1 = (const float*)d_in[4];
    const float* beta1  = (const float*)d_in[5];
    const float* W2     = (const float*)d_in[6];
    const float* b2     = (const float*)d_in[7];
    float* out = (float*)d_out;

    int N = in_sizes[0] / DIN;
    int E = in_sizes[1] / 2;
    const int* src = ei;
    const int* dst = ei + E;
    int nbk = (N + BK - 1) >> BKSH;         // 782
    int chunk = (E + G - 1) / G;

    size_t off = 0;  // 4B units
    auto alloc = [&](size_t elems) -> void* {
        void* p = (char*)d_ws + off * 4;
        off += (elems + 127) & ~size_t(127);
        return p;
    };
    int*            hist_g = (int*)alloc((size_t)G * NBK_MAX);
    int*            rowoff = (int*)alloc((size_t)G * NBK_MAX);            // g-major [G][nbk]
    int*            tot    = (int*)alloc(NBK_MAX);
    unsigned*       recs   = (unsigned*)alloc((size_t)NBK_MAX * CAP);     // fixed-CAP regions
    int*            col    = (int*)alloc((size_t)NBK_MAX * CCAP);         // padded-to-8 CSR cols
    float*          dis    = (float*)alloc(N);
    int2*           rpde   = (int2*)alloc((size_t)N * 2);
    float*          stats  = (float*)alloc(128);
    unsigned short* h1s    = (unsigned short*)alloc((size_t)(N + 1) * DH / 2);  // bf16, +1 sentinel row
    unsigned short* agg1b  = (unsigned short*)alloc((size_t)N * DH / 2);        // bf16
    unsigned short* h2s    = h1s;  // h1s dead after agg1_k; row N (32 bf16) fits inside region

    hipMemsetAsync(stats, 0, 128 * sizeof(float), stream);

    hist_k<<<G, 512, 0, stream>>>(dst, hist_g, E, nbk, chunk);
    scan_k<<<(nbk + 15) / 16, 256, 0, stream>>>(hist_g, rowoff, tot, nbk);
    scatter_k<<<G, 512, 0, stream>>>(src, dst, rowoff, recs, E, nbk, chunk);
    csr_k<<<nbk, 512, 0, stream>>>(recs, tot, dis, rpde, col, N);

    gemm1_k<<<(N + 63) / 64, 256, 0, stream>>>(x, W1, dis, h1s, N);
    agg1_k<<<(N + 3) / 4, 256, 0, stream>>>((const unsigned*)h1s, rpde, col, (unsigned*)agg1b, N);

    bnstats_k<<<400, 256, 0, stream>>>(agg1b, stats, N);

    gemm2_k<<<(N + 63) / 64, 256, 0, stream>>>(agg1b, W2, stats, gamma1, beta1, dis, h2s,
                                               1.0f / (float)N, N);
    agg2_k<<<(N + 7) / 8, 256, 0, stream>>>((const unsigned*)h2s, rpde, col, b2, out, N);
}

// Round 2
// 258.804 us; speedup vs baseline: 1.0006x; 1.0006x over previous
//
#include <hip/hip_runtime.h>

#define DIN 128
#define DH 64
#define DOUT 32
#define BN_EPS 1e-5f

#define BK 128          // nodes per bucket
#define BKSH 7          // log2(BK)
#define NBK_MAX 784     // ceil(100000/128)=782, padded
#define G 256           // counting-sort partition blocks; 32/XCD open-line set ~3.2MB fits L2
#define CAP 2560        // fixed per-bucket region capacity (mean 2048, +11 sigma)
#define CCAP 3584       // col region capacity: CAP + 128 nodes * 7 max pad (pad-to-8 sentinel)

typedef __attribute__((ext_vector_type(8))) short short8;
typedef __attribute__((ext_vector_type(4))) float floatx4;

// bf16 helpers (RNE store, exact load)
__device__ __forceinline__ unsigned short f2bf(float f) {
    union { float f; unsigned u; } v; v.f = f;
    unsigned r = (v.u + 0x7FFFu + ((v.u >> 16) & 1u)) >> 16;
    return (unsigned short)r;
}
__device__ __forceinline__ float bf2f(unsigned short h) {
    union { unsigned u; float f; } v; v.u = ((unsigned)h) << 16;
    return v.f;
}
__device__ __forceinline__ float lo_f(unsigned u) {
    union { unsigned u; float f; } v; v.u = u << 16;
    return v.f;
}
__device__ __forceinline__ float hi_f(unsigned u) {
    union { unsigned u; float f; } v; v.u = u & 0xFFFF0000u;
    return v.f;
}
__device__ __forceinline__ unsigned pack2bf(float lo, float hi) {
    return (unsigned)f2bf(lo) | ((unsigned)f2bf(hi) << 16);
}

// ---------------- counting sort pass 1: per-block bucket histogram (g-major write) ----------------

__global__ __launch_bounds__(512) void hist_k(const int* __restrict__ dst, int* __restrict__ hist_g,
                                              int E, int nbk, int chunk) {
    __shared__ int hist[NBK_MAX];
    int g = blockIdx.x, tid = threadIdx.x;
    for (int b = tid; b < nbk; b += 512) hist[b] = 0;
    __syncthreads();
    int i0 = g * chunk, iend = min(i0 + chunk, E);
    for (int i = i0 + tid; i < iend; i += 512)
        atomicAdd(&hist[dst[i] >> BKSH], 1);
    __syncthreads();
    for (int b = tid; b < nbk; b += 512)
        hist_g[(size_t)g * nbk + b] = hist[b];   // coalesced row write
}

// ---------------- pass 2: per-bucket exclusive scan over the G=256 block-counts ----------------

__global__ __launch_bounds__(256) void scan_k(const int* __restrict__ hist_g, int* __restrict__ rowoff,
                                              int* __restrict__ tot, int nbk) {
    __shared__ int seg[16][17];
    int tid = threadIdx.x;
    int gl = tid >> 4, bl = tid & 15;
    int b = blockIdx.x * 16 + bl;
    bool bok = b < nbk;
    int vals[16];
    int psum = 0;
    #pragma unroll
    for (int j = 0; j < 16; j++) {
        int g = gl * 16 + j;
        int v = bok ? hist_g[(size_t)g * nbk + b] : 0;   // 16 independent loads in flight
        vals[j] = v; psum += v;
    }
    seg[gl][bl] = psum;
    __syncthreads();
    #pragma unroll
    for (int off = 1; off < 16; off <<= 1) {
        int t = (gl >= off) ? seg[gl - off][bl] : 0;
        __syncthreads();
        seg[gl][bl] += t;
        __syncthreads();
    }
    int run = seg[gl][bl] - psum;                        // exclusive base of this 16-g segment
    if (gl == 15 && bok) tot[b] = seg[15][bl];
    #pragma unroll
    for (int j = 0; j < 16; j++) {
        int g = gl * 16 + j;
        if (bok) rowoff[(size_t)g * nbk + b] = run;      // g-major: scatter_k reads rows coalesced
        run += vals[j];
    }
}

// ---------------- pass 3: scatter records into fixed-CAP bucket regions (no global atomics) ----------------

__global__ __launch_bounds__(512) void scatter_k(const int* __restrict__ src, const int* __restrict__ dst,
                                                 const int* __restrict__ rowoff,
                                                 unsigned* __restrict__ recs, int E, int nbk, int chunk) {
    __shared__ int cur[NBK_MAX];
    int g = blockIdx.x, tid = threadIdx.x;
    for (int b = tid; b < nbk; b += 512)
        cur[b] = b * CAP + rowoff[(size_t)g * nbk + b];   // coalesced row read (g-major)
    __syncthreads();
    int i0 = g * chunk, iend = min(i0 + chunk, E);
    for (int i = i0 + tid; i < iend; i += 512) {
        int s = src[i], d = dst[i];
        int b = d >> BKSH;
        int slot = atomicAdd(&cur[b], 1);   // LDS atomic
        if (slot < (b + 1) * CAP)           // overflow guard (never fires at CAP=mean+11sigma)
            recs[slot] = ((unsigned)s << BKSH) | (unsigned)(d & (BK - 1));
    }
}

// ---------------- pass 4: within-bucket node sort -> CSR (pad-to-8, sentinel n), wave-private cursors ----------------

__global__ __launch_bounds__(512) void csr_k(const unsigned* __restrict__ recs, const int* __restrict__ tot,
                                             float* __restrict__ dis, int2* __restrict__ rpde,
                                             int* __restrict__ col, int n) {
    __shared__ int deg8[8][BK];   // 4 KB
    __shared__ int wb[8][BK];     // 4 KB
    __shared__ int deg[BK], sc[BK], bas[BK];
    int b = blockIdx.x, tid = threadIdx.x;
    int w = tid >> 6, lane = tid & 63;
    for (int i = tid; i < 8 * BK; i += 512) ((int*)deg8)[i] = 0;
    __syncthreads();
    int lo = b * CAP;            // recs region (stride CAP)
    int clo = b * CCAP;          // col region (stride CCAP, has room for padding)
    int ne = min(tot[b], CAP);
    int hi = lo + ne;
    for (int e = lo + w * 64 + lane; e < hi; e += 512)
        atomicAdd(&deg8[w][recs[e] & (BK - 1)], 1);
    __syncthreads();
    if (tid < BK) {
        int run = 0;
        #pragma unroll
        for (int ww = 0; ww < 8; ww++) { wb[ww][tid] = run; run += deg8[ww][tid]; }
        deg[tid] = run;
        sc[tid] = (run + 7) & ~7;                 // scan over PADDED degree
    }
    __syncthreads();
    for (int off = 1; off < BK; off <<= 1) {
        int t = (tid < BK && tid >= off) ? sc[tid - off] : 0;
        __syncthreads();
        if (tid < BK) sc[tid] += t;
        __syncthreads();
    }
    if (tid < BK) {
        int d = deg[tid];
        int pdeg = (d + 7) & ~7;
        int base = sc[tid] - pdeg;
        bas[tid] = base;
        int g = b * BK + tid;
        if (g < n) {
            dis[g] = rsqrtf((float)(d + 1));      // +1 self-loop
            rpde[g] = make_int2(clo + base, d);
        }
        for (int j = d; j < pdeg; j++)            // sentinel padding (<=7 per node)
            col[clo + base + j] = n;
    }
    __syncthreads();
    for (int i = tid; i < 8 * BK; i += 512)
        ((int*)wb)[i] += bas[i & (BK - 1)];       // wb[w][dl] += bas[dl]
    __syncthreads();
    for (int e = lo + w * 64 + lane; e < hi; e += 512) {
        unsigned r = recs[e];
        int dl = r & (BK - 1);
        int k = atomicAdd(&wb[w][dl], 1);         // wave-private cursor
        col[clo + k] = (int)(r >> BKSH);
    }
}

// ---------------- GEMM1 (MFMA bf16): h1s = bf16((x @ W1) * dis[row]); row n = zero sentinel ----------------

__global__ __launch_bounds__(256) void gemm1_k(const float* __restrict__ x,
                                               const float* __restrict__ W1,
                                               const float* __restrict__ dis,
                                               unsigned short* __restrict__ h1s, int n) {
    __shared__ unsigned short xb[64][136];   // +8 pad: rows 272B apart -> 2-way bank alias (free)
    __shared__ unsigned short wt[64][136];
    int tid = threadIdx.x;
    int r0b = blockIdx.x * 64;

    for (int c = tid; c < 2048; c += 256) {
        int k = c >> 4, n4 = (c & 15) * 4;
        float4 v = ((const float4*)W1)[c];
        wt[n4 + 0][k] = f2bf(v.x);
        wt[n4 + 1][k] = f2bf(v.y);
        wt[n4 + 2][k] = f2bf(v.z);
        wt[n4 + 3][k] = f2bf(v.w);
    }
    for (int c = tid; c < 2048; c += 256) {
        int r = c >> 5, k4 = (c & 31) * 4;
        int gr = r0b + r;
        float4 v = make_float4(0.f, 0.f, 0.f, 0.f);
        if (gr < n) v = ((const float4*)x)[(gr << 5) + (k4 >> 2)];
        ushort4 o;
        o.x = f2bf(v.x); o.y = f2bf(v.y); o.z = f2bf(v.z); o.w = f2bf(v.w);
        *(ushort4*)&xb[r][k4] = o;
    }
    __syncthreads();

    int w = tid >> 6, lane = tid & 63;
    int rr = lane & 15, q = lane >> 4;
    floatx4 acc0 = {0.f, 0.f, 0.f, 0.f}, acc1 = acc0, acc2 = acc0, acc3 = acc0;
    #pragma unroll
    for (int kt = 0; kt < 4; kt++) {
        int k0 = kt * 32 + q * 8;
        short8 a  = *(const short8*)&xb[w * 16 + rr][k0];
        short8 b0 = *(const short8*)&wt[rr][k0];
        short8 b1 = *(const short8*)&wt[16 + rr][k0];
        short8 b2 = *(const short8*)&wt[32 + rr][k0];
        short8 b3 = *(const short8*)&wt[48 + rr][k0];
        acc0 = __builtin_amdgcn_mfma_f32_16x16x32_bf16(a, b0, acc0, 0, 0, 0);
        acc1 = __builtin_amdgcn_mfma_f32_16x16x32_bf16(a, b1, acc1, 0, 0, 0);
        acc2 = __builtin_amdgcn_mfma_f32_16x16x32_bf16(a, b2, acc2, 0, 0, 0);
        acc3 = __builtin_amdgcn_mfma_f32_16x16x32_bf16(a, b3, acc3, 0, 0, 0);
    }
    #pragma unroll
    for (int t = 0; t < 4; t++) {
        int gr = r0b + w * 16 + q * 4 + t;
        if (gr < n) {
            float dd = dis[gr];
            unsigned short* o = &h1s[gr * 64];
            o[rr]      = f2bf(acc0[t] * dd);
            o[16 + rr] = f2bf(acc1[t] * dd);
            o[32 + rr] = f2bf(acc2[t] * dd);
            o[48 + rr] = f2bf(acc3[t] * dd);
        } else if (gr == n) {                    // sentinel zero row for padded gathers
            unsigned short* o = &h1s[gr * 64];
            o[rr] = 0; o[16 + rr] = 0; o[32 + rr] = 0; o[48 + rr] = 0;
        }
    }
}

// ---------------- Aggregation layer 1: wave per node, one guarded 32-edge chunk ----------------
// Deg is Poisson(16): P(deg>32) ~ 1e-4, so nearly every node is ONE chunk = 8 col loads
// + 8 dwordx2 gathers ALL in flight (16 outstanding VMEM/wave). Guards select the col VALUE
// to sentinel n (zero row) via min-clamp + cndmask -- no exec divergence, no tail.

__global__ __launch_bounds__(256) void agg1_k(const unsigned* __restrict__ h1p,
                                              const int2* __restrict__ rpde,
                                              const int* __restrict__ col,
                                              unsigned* __restrict__ outp, int n) {
    int node = (blockIdx.x * 256 + threadIdx.x) >> 6;
    int lane = threadIdx.x & 63;
    if (node >= n) return;
    int f2 = lane & 15, eslot = lane >> 4;
    int2 rd = rpde[node];
    int e  = __builtin_amdgcn_readfirstlane(rd.x);
    int dg = __builtin_amdgcn_readfirstlane(rd.y);
    int pdg = (dg + 7) & ~7;
    int pm1 = pdg - 1;

    const uint2* h1q = (const uint2*)h1p;        // 16 uint2 per row
    float a0 = 0.f, b0 = 0.f, c0 = 0.f, d0 = 0.f;
    float a1 = 0.f, b1 = 0.f, c1 = 0.f, d1 = 0.f;
    float a2 = 0.f, b2 = 0.f, c2 = 0.f, d2 = 0.f;
    float a3 = 0.f, b3 = 0.f, c3 = 0.f, d3 = 0.f;
    for (int b = 0; b < pdg; b += 32) {
        int i0 = b + 0  + eslot, i1 = b + 4  + eslot, i2 = b + 8  + eslot, i3 = b + 12 + eslot;
        int i4 = b + 16 + eslot, i5 = b + 20 + eslot, i6 = b + 24 + eslot, i7 = b + 28 + eslot;
        // 8 independent col loads (clamped addr), then value-guard to sentinel n
        int s0 = col[e + min(i0, pm1)], s1 = col[e + min(i1, pm1)];
        int s2 = col[e + min(i2, pm1)], s3 = col[e + min(i3, pm1)];
        int s4 = col[e + min(i4, pm1)], s5 = col[e + min(i5, pm1)];
        int s6 = col[e + min(i6, pm1)], s7 = col[e + min(i7, pm1)];
        s0 = (i0 <= pm1) ? s0 : n;  s1 = (i1 <= pm1) ? s1 : n;
        s2 = (i2 <= pm1) ? s2 : n;  s3 = (i3 <= pm1) ? s3 : n;
        s4 = (i4 <= pm1) ? s4 : n;  s5 = (i5 <= pm1) ? s5 : n;
        s6 = (i6 <= pm1) ? s6 : n;  s7 = (i7 <= pm1) ? s7 : n;
        // 8 dwordx2 gathers, all in flight
        uint2 u0 = h1q[s0 * 16 + f2], u1 = h1q[s1 * 16 + f2];
        uint2 u2 = h1q[s2 * 16 + f2], u3 = h1q[s3 * 16 + f2];
        uint2 u4 = h1q[s4 * 16 + f2], u5 = h1q[s5 * 16 + f2];
        uint2 u6 = h1q[s6 * 16 + f2], u7 = h1q[s7 * 16 + f2];
        a0 += lo_f(u0.x); b0 += hi_f(u0.x); c0 += lo_f(u0.y); d0 += hi_f(u0.y);
        a1 += lo_f(u1.x); b1 += hi_f(u1.x); c1 += lo_f(u1.y); d1 += hi_f(u1.y);
        a2 += lo_f(u2.x); b2 += hi_f(u2.x); c2 += lo_f(u2.y); d2 += hi_f(u2.y);
        a3 += lo_f(u3.x); b3 += hi_f(u3.x); c3 += lo_f(u3.y); d3 += hi_f(u3.y);
        a0 += lo_f(u4.x); b0 += hi_f(u4.x); c0 += lo_f(u4.y); d0 += hi_f(u4.y);
        a1 += lo_f(u5.x); b1 += hi_f(u5.x); c1 += lo_f(u5.y); d1 += hi_f(u5.y);
        a2 += lo_f(u6.x); b2 += hi_f(u6.x); c2 += lo_f(u6.y); d2 += hi_f(u6.y);
        a3 += lo_f(u7.x); b3 += hi_f(u7.x); c3 += lo_f(u7.y); d3 += hi_f(u7.y);
    }
    float ax = (a0 + a1) + (a2 + a3), bx = (b0 + b1) + (b2 + b3);
    float ay = (c0 + c1) + (c2 + c3), by = (d0 + d1) + (d2 + d3);
    ax += __shfl_xor(ax, 16, 64); ax += __shfl_xor(ax, 32, 64);
    bx += __shfl_xor(bx, 16, 64); bx += __shfl_xor(bx, 32, 64);
    ay += __shfl_xor(ay, 16, 64); ay += __shfl_xor(ay, 32, 64);
    by += __shfl_xor(by, 16, 64); by += __shfl_xor(by, 32, 64);
    if (eslot == 0) {
        uint2 us = h1q[node * 16 + f2];
        float dn = rsqrtf((float)(dg + 1));
        uint2 o;
        o.x = pack2bf((ax + lo_f(us.x)) * dn, (bx + hi_f(us.x)) * dn);
        o.y = pack2bf((ay + lo_f(us.y)) * dn, (by + hi_f(us.y)) * dn);
        ((uint2*)outp)[node * 16 + f2] = o;
    }
}

// ---------------- BN stats (bf16 input) ----------------

__global__ __launch_bounds__(256) void bnstats_k(const unsigned short* __restrict__ agg1b,
                                                 float* __restrict__ stats, int n) {
    int f = threadIdx.x & 63, g = threadIdx.x >> 6;
    float sum = 0.f, sq = 0.f;
    for (int r = blockIdx.x * 4 + g; r < n; r += gridDim.x * 4) {
        float v = bf2f(agg1b[r * 64 + f]);
        sum += v; sq += v * v;
    }
    __shared__ float s1[4][64], s2[4][64];
    s1[g][f] = sum; s2[g][f] = sq;
    __syncthreads();
    if (g == 0) {
        sum = s1[0][f] + s1[1][f] + s1[2][f] + s1[3][f];
        sq  = s2[0][f] + s2[1][f] + s2[2][f] + s2[3][f];
        atomicAdd(&stats[f], sum);
        atomicAdd(&stats[64 + f], sq);
    }
}

// ---------------- GEMM2 (MFMA bf16), BN fold inlined: h2s = bf16((relu(agg1b*s+t) @ W2) * dis[row]) ----------------

__global__ __launch_bounds__(256) void gemm2_k(const unsigned short* __restrict__ agg1b,
                                               const float* __restrict__ W2,
                                               const float* __restrict__ stats,
                                               const float* __restrict__ gamma, const float* __restrict__ beta,
                                               const float* __restrict__ dis,
                                               unsigned short* __restrict__ h2s, float invn, int n) {
    __shared__ unsigned short ab[64][72];    // +8 pad
    __shared__ unsigned short wt[32][72];
    __shared__ float s_s[64], s_t[64];
    int tid = threadIdx.x;
    int r0b = blockIdx.x * 64;
    if (tid < 64) {                          // BN fold (b1 cancels by shift invariance)
        float mean = stats[tid] * invn;
        float var = stats[64 + tid] * invn - mean * mean;
        float s = gamma[tid] * rsqrtf(var + BN_EPS);
        s_s[tid] = s;
        s_t[tid] = beta[tid] - mean * s;
    }
    for (int c = tid; c < 512; c += 256) {   // stage W2^T (512 float4)
        int k = c >> 3, n4 = (c & 7) * 4;
        float4 v = ((const float4*)W2)[c];
        wt[n4 + 0][k] = f2bf(v.x);
        wt[n4 + 1][k] = f2bf(v.y);
        wt[n4 + 2][k] = f2bf(v.z);
        wt[n4 + 3][k] = f2bf(v.w);
    }
    __syncthreads();
    for (int c = tid; c < 512; c += 256) {
        int r = c >> 3, k0 = (c & 7) * 8;
        int gr = r0b + r;
        unsigned short tmp[8];
        if (gr < n) {
            const unsigned short* ap = &agg1b[gr * 64 + k0];
            #pragma unroll
            for (int j = 0; j < 8; j++)
                tmp[j] = f2bf(fmaxf(bf2f(ap[j]) * s_s[k0 + j] + s_t[k0 + j], 0.f));
        } else {
            #pragma unroll
            for (int j = 0; j < 8; j++) tmp[j] = 0;
        }
        *(short8*)&ab[r][k0] = *(short8*)tmp;
    }
    __syncthreads();

    int w = tid >> 6, lane = tid & 63;
    int rr = lane & 15, q = lane >> 4;
    floatx4 acc0 = {0.f, 0.f, 0.f, 0.f}, acc1 = acc0;
    #pragma unroll
    for (int kt = 0; kt < 2; kt++) {
        int k0 = kt * 32 + q * 8;
        short8 a  = *(const short8*)&ab[w * 16 + rr][k0];
        short8 b0 = *(const short8*)&wt[rr][k0];
        short8 b1 = *(const short8*)&wt[16 + rr][k0];
        acc0 = __builtin_amdgcn_mfma_f32_16x16x32_bf16(a, b0, acc0, 0, 0, 0);
        acc1 = __builtin_amdgcn_mfma_f32_16x16x32_bf16(a, b1, acc1, 0, 0, 0);
    }
    #pragma unroll
    for (int t = 0; t < 4; t++) {
        int gr = r0b + w * 16 + q * 4 + t;
        if (gr < n) {
            float dd = dis[gr];
            h2s[gr * 32 + rr]      = f2bf(acc0[t] * dd);
            h2s[gr * 32 + 16 + rr] = f2bf(acc1[t] * dd);
        } else if (gr == n) {                // sentinel zero row for padded gathers
            h2s[gr * 32 + rr]      = 0;
            h2s[gr * 32 + 16 + rr] = 0;
        }
    }
}

// ---------------- Aggregation layer 2: node per half-wave, one guarded 32-edge chunk ----------------

__global__ __launch_bounds__(256) void agg2_k(const unsigned* __restrict__ h2p,
                                              const int2* __restrict__ rpde,
                                              const int* __restrict__ col, const float* __restrict__ b2,
                                              float* __restrict__ out, int n) {
    int wave = (blockIdx.x * 256 + threadIdx.x) >> 6;
    int lane = threadIdx.x & 63;
    int half = lane >> 5, hl = lane & 31;
    int node = wave * 2 + half;
    if (node >= n) return;
    int f2 = hl & 7, eslot = hl >> 3;        // uint2 column of 8-uint2 row; eslot in [0,4)
    int2 rd = rpde[node];                    // uniform within half
    int e = rd.x, dg = rd.y;
    int pdg = (dg + 7) & ~7;
    int pm1 = pdg - 1;

    const uint2* h2q = (const uint2*)h2p;    // 8 uint2 per row
    float a0 = 0.f, b0 = 0.f, c0 = 0.f, d0 = 0.f;
    float a1 = 0.f, b1 = 0.f, c1 = 0.f, d1 = 0.f;
    float a2 = 0.f, b2f = 0.f, c2 = 0.f, d2 = 0.f;
    float a3 = 0.f, b3 = 0.f, c3 = 0.f, d3 = 0.f;
    for (int b = 0; b < pdg; b += 32) {
        int i0 = b + 0  + eslot, i1 = b + 4  + eslot, i2 = b + 8  + eslot, i3 = b + 12 + eslot;
        int i4 = b + 16 + eslot, i5 = b + 20 + eslot, i6 = b + 24 + eslot, i7 = b + 28 + eslot;
        int s0 = col[e + min(i0, pm1)], s1 = col[e + min(i1, pm1)];
        int s2 = col[e + min(i2, pm1)], s3 = col[e + min(i3, pm1)];
        int s4 = col[e + min(i4, pm1)], s5 = col[e + min(i5, pm1)];
        int s6 = col[e + min(i6, pm1)], s7 = col[e + min(i7, pm1)];
        s0 = (i0 <= pm1) ? s0 : n;  s1 = (i1 <= pm1) ? s1 : n;
        s2 = (i2 <= pm1) ? s2 : n;  s3 = (i3 <= pm1) ? s3 : n;
        s4 = (i4 <= pm1) ? s4 : n;  s5 = (i5 <= pm1) ? s5 : n;
        s6 = (i6 <= pm1) ? s6 : n;  s7 = (i7 <= pm1) ? s7 : n;
        uint2 u0 = h2q[s0 * 8 + f2], u1 = h2q[s1 * 8 + f2];
        uint2 u2 = h2q[s2 * 8 + f2], u3 = h2q[s3 * 8 + f2];
        uint2 u4 = h2q[s4 * 8 + f2], u5 = h2q[s5 * 8 + f2];
        uint2 u6 = h2q[s6 * 8 + f2], u7 = h2q[s7 * 8 + f2];
        a0 += lo_f(u0.x); b0 += hi_f(u0.x); c0 += lo_f(u0.y); d0 += hi_f(u0.y);
        a1 += lo_f(u1.x); b1 += hi_f(u1.x); c1 += lo_f(u1.y); d1 += hi_f(u1.y);
        a2 += lo_f(u2.x); b2f += hi_f(u2.x); c2 += lo_f(u2.y); d2 += hi_f(u2.y);
        a3 += lo_f(u3.x); b3 += hi_f(u3.x); c3 += lo_f(u3.y); d3 += hi_f(u3.y);
        a0 += lo_f(u4.x); b0 += hi_f(u4.x); c0 += lo_f(u4.y); d0 += hi_f(u4.y);
        a1 += lo_f(u5.x); b1 += hi_f(u5.x); c1 += lo_f(u5.y); d1 += hi_f(u5.y);
        a2 += lo_f(u6.x); b2f += hi_f(u6.x); c2 += lo_f(u6.y); d2 += hi_f(u6.y);
        a3 += lo_f(u7.x); b3 += hi_f(u7.x); c3 += lo_f(u7.y); d3 += hi_f(u7.y);
    }
    float ax = (a0 + a1) + (a2 + a3), bx = (b0 + b1) + (b2f + b3);
    float ay = (c0 + c1) + (c2 + c3), by = (d0 + d1) + (d2 + d3);
    ax += __shfl_xor(ax, 8, 64); ax += __shfl_xor(ax, 16, 64);
    bx += __shfl_xor(bx, 8, 64); bx += __shfl_xor(bx, 16, 64);
    ay += __shfl_xor(ay, 8, 64); ay += __shfl_xor(ay, 16, 64);
    by += __shfl_xor(by, 8, 64); by += __shfl_xor(by, 16, 64);
    if (eslot == 0) {
        uint2 us = h2q[node * 8 + f2];
        float dn = rsqrtf((float)(dg + 1));
        float4 bb = ((const float4*)b2)[f2];
        float4 o;
        o.x = (ax + lo_f(us.x)) * dn + bb.x;
        o.y = (bx + hi_f(us.x)) * dn + bb.y;
        o.z = (ay + lo_f(us.y)) * dn + bb.z;
        o.w = (by + hi_f(us.y)) * dn + bb.w;
        ((float4*)out)[node * 8 + f2] = o;
    }
}

// ---------------- launch ----------------

extern "C" void kernel_launch(void* const* d_in, const int* in_sizes, int n_in,
                              void* d_out, int out_size, void* d_ws, size_t ws_size,
                              hipStream_t stream) {
    const float* x      = (const float*)d_in[0];
    const int*   ei     = (const int*)d_in[1];
    const float* W1     = (const float*)d_in[2];
    // d_in[3] = b1 (cancels inside BN)
    const float* gamma1 = (const float*)d_in[4];
    const float* beta1  = (const float*)d_in[5];
    const float* W2     = (const float*)d_in[6];
    const float* b2     = (const float*)d_in[7];
    float* out = (float*)d_out;

    int N = in_sizes[0] / DIN;
    int E = in_sizes[1] / 2;
    const int* src = ei;
    const int* dst = ei + E;
    int nbk = (N + BK - 1) >> BKSH;         // 782
    int chunk = (E + G - 1) / G;

    size_t off = 0;  // 4B units
    auto alloc = [&](size_t elems) -> void* {
        void* p = (char*)d_ws + off * 4;
        off += (elems + 127) & ~size_t(127);
        return p;
    };
    int*            hist_g = (int*)alloc((size_t)G * NBK_MAX);
    int*            rowoff = (int*)alloc((size_t)G * NBK_MAX);            // g-major [G][nbk]
    int*            tot    = (int*)alloc(NBK_MAX);
    unsigned*       recs   = (unsigned*)alloc((size_t)NBK_MAX * CAP);     // fixed-CAP regions
    int*            col    = (int*)alloc((size_t)NBK_MAX * CCAP);         // padded-to-8 CSR cols
    float*          dis    = (float*)alloc(N);
    int2*           rpde   = (int2*)alloc((size_t)N * 2);
    float*          stats  = (float*)alloc(128);
    unsigned short* h1s    = (unsigned short*)alloc((size_t)(N + 1) * DH / 2);  // bf16, +1 sentinel row
    unsigned short* agg1b  = (unsigned short*)alloc((size_t)N * DH / 2);        // bf16
    unsigned short* h2s    = h1s;  // h1s dead after agg1_k; row N (32 bf16) fits inside region

    hipMemsetAsync(stats, 0, 128 * sizeof(float), stream);

    hist_k<<<G, 512, 0, stream>>>(dst, hist_g, E, nbk, chunk);
    scan_k<<<(nbk + 15) / 16, 256, 0, stream>>>(hist_g, rowoff, tot, nbk);
    scatter_k<<<G, 512, 0, stream>>>(src, dst, rowoff, recs, E, nbk, chunk);
    csr_k<<<nbk, 512, 0, stream>>>(recs, tot, dis, rpde, col, N);

    gemm1_k<<<(N + 63) / 64, 256, 0, stream>>>(x, W1, dis, h1s, N);
    agg1_k<<<(N + 3) / 4, 256, 0, stream>>>((const unsigned*)h1s, rpde, col, (unsigned*)agg1b, N);

    bnstats_k<<<400, 256, 0, stream>>>(agg1b, stats, N);

    gemm2_k<<<(N + 63) / 64, 256, 0, stream>>>(agg1b, W2, stats, gamma1, beta1, dis, h2s,
                                               1.0f / (float)N, N);
    agg2_k<<<(N + 7) / 8, 256, 0, stream>>>((const unsigned*)h2s, rpde, col, b2, out, N);
}

// Round 3
// 253.847 us; speedup vs baseline: 1.0202x; 1.0195x over previous
//
#include <hip/hip_runtime.h>

#define DIN 128
#define DH 64
#define DOUT 32
#define BN_EPS 1e-5f

#define BK 128          // nodes per bucket
#define BKSH 7          // log2(BK)
#define NBK_MAX 784     // ceil(100000/128)=782, padded
#define G 256           // counting-sort partition blocks; 32/XCD open-line set ~3.2MB fits L2
#define CAP 2560        // fixed per-bucket region capacity (mean 2048, +11 sigma)
#define CCAP 3584       // col region capacity: CAP + 128 nodes * 7 max pad (pad-to-8 sentinel)

typedef __attribute__((ext_vector_type(8))) short short8;
typedef __attribute__((ext_vector_type(4))) float floatx4;

// bf16 helpers (RNE store, exact load)
__device__ __forceinline__ unsigned short f2bf(float f) {
    union { float f; unsigned u; } v; v.f = f;
    unsigned r = (v.u + 0x7FFFu + ((v.u >> 16) & 1u)) >> 16;
    return (unsigned short)r;
}
__device__ __forceinline__ float bf2f(unsigned short h) {
    union { unsigned u; float f; } v; v.u = ((unsigned)h) << 16;
    return v.f;
}
__device__ __forceinline__ float lo_f(unsigned u) {
    union { unsigned u; float f; } v; v.u = u << 16;
    return v.f;
}
__device__ __forceinline__ float hi_f(unsigned u) {
    union { unsigned u; float f; } v; v.u = u & 0xFFFF0000u;
    return v.f;
}
__device__ __forceinline__ unsigned pack2bf(float lo, float hi) {
    return (unsigned)f2bf(lo) | ((unsigned)f2bf(hi) << 16);
}

#define LOX(u) lo_f((u).x)
#define HIX(u) hi_f((u).x)
#define LOY(u) lo_f((u).y)
#define HIY(u) hi_f((u).y)
#define SUM8(F,u0,u1,u2,u3,u4,u5,u6,u7) \
    (((F(u0)+F(u1))+(F(u2)+F(u3)))+((F(u4)+F(u5))+(F(u6)+F(u7))))

// ---------------- counting sort pass 1: per-block bucket histogram (g-major write) ----------------

__global__ __launch_bounds__(512) void hist_k(const int* __restrict__ dst, int* __restrict__ hist_g,
                                              int E, int nbk, int chunk) {
    __shared__ int hist[NBK_MAX];
    int g = blockIdx.x, tid = threadIdx.x;
    for (int b = tid; b < nbk; b += 512) hist[b] = 0;
    __syncthreads();
    int i0 = g * chunk, iend = min(i0 + chunk, E);
    for (int i = i0 + tid; i < iend; i += 512)
        atomicAdd(&hist[dst[i] >> BKSH], 1);
    __syncthreads();
    for (int b = tid; b < nbk; b += 512)
        hist_g[(size_t)g * nbk + b] = hist[b];   // coalesced row write
}

// ---------------- pass 2: per-bucket exclusive scan over the G=256 block-counts ----------------

__global__ __launch_bounds__(256) void scan_k(const int* __restrict__ hist_g, int* __restrict__ rowoff,
                                              int* __restrict__ tot, int nbk) {
    __shared__ int seg[16][17];
    int tid = threadIdx.x;
    int gl = tid >> 4, bl = tid & 15;
    int b = blockIdx.x * 16 + bl;
    bool bok = b < nbk;
    int vals[16];
    int psum = 0;
    #pragma unroll
    for (int j = 0; j < 16; j++) {
        int g = gl * 16 + j;
        int v = bok ? hist_g[(size_t)g * nbk + b] : 0;   // 16 independent loads in flight
        vals[j] = v; psum += v;
    }
    seg[gl][bl] = psum;
    __syncthreads();
    #pragma unroll
    for (int off = 1; off < 16; off <<= 1) {
        int t = (gl >= off) ? seg[gl - off][bl] : 0;
        __syncthreads();
        seg[gl][bl] += t;
        __syncthreads();
    }
    int run = seg[gl][bl] - psum;                        // exclusive base of this 16-g segment
    if (gl == 15 && bok) tot[b] = seg[15][bl];
    #pragma unroll
    for (int j = 0; j < 16; j++) {
        int g = gl * 16 + j;
        if (bok) rowoff[(size_t)g * nbk + b] = run;      // g-major: scatter_k reads rows coalesced
        run += vals[j];
    }
}

// ---------------- pass 3: scatter records into fixed-CAP bucket regions (no global atomics) ----------------

__global__ __launch_bounds__(512) void scatter_k(const int* __restrict__ src, const int* __restrict__ dst,
                                                 const int* __restrict__ rowoff,
                                                 unsigned* __restrict__ recs, int E, int nbk, int chunk) {
    __shared__ int cur[NBK_MAX];
    int g = blockIdx.x, tid = threadIdx.x;
    for (int b = tid; b < nbk; b += 512)
        cur[b] = b * CAP + rowoff[(size_t)g * nbk + b];   // coalesced row read (g-major)
    __syncthreads();
    int i0 = g * chunk, iend = min(i0 + chunk, E);
    for (int i = i0 + tid; i < iend; i += 512) {
        int s = src[i], d = dst[i];
        int b = d >> BKSH;
        int slot = atomicAdd(&cur[b], 1);   // LDS atomic
        if (slot < (b + 1) * CAP)           // overflow guard (never fires at CAP=mean+11sigma)
            recs[slot] = ((unsigned)s << BKSH) | (unsigned)(d & (BK - 1));
    }
}

// ---------------- pass 4: within-bucket node sort -> CSR (pad-to-8, sentinel n), wave-private cursors ----------------

__global__ __launch_bounds__(512) void csr_k(const unsigned* __restrict__ recs, const int* __restrict__ tot,
                                             float* __restrict__ dis, int2* __restrict__ rpde,
                                             int* __restrict__ col, int n) {
    __shared__ int deg8[8][BK];   // 4 KB
    __shared__ int wb[8][BK];     // 4 KB
    __shared__ int deg[BK], sc[BK], bas[BK];
    int b = blockIdx.x, tid = threadIdx.x;
    int w = tid >> 6, lane = tid & 63;
    for (int i = tid; i < 8 * BK; i += 512) ((int*)deg8)[i] = 0;
    __syncthreads();
    int lo = b * CAP;            // recs region (stride CAP)
    int clo = b * CCAP;          // col region (stride CCAP, has room for padding)
    int ne = min(tot[b], CAP);
    int hi = lo + ne;
    for (int e = lo + w * 64 + lane; e < hi; e += 512)
        atomicAdd(&deg8[w][recs[e] & (BK - 1)], 1);
    __syncthreads();
    if (tid < BK) {
        int run = 0;
        #pragma unroll
        for (int ww = 0; ww < 8; ww++) { wb[ww][tid] = run; run += deg8[ww][tid]; }
        deg[tid] = run;
        sc[tid] = (run + 7) & ~7;                 // scan over PADDED degree
    }
    __syncthreads();
    for (int off = 1; off < BK; off <<= 1) {
        int t = (tid < BK && tid >= off) ? sc[tid - off] : 0;
        __syncthreads();
        if (tid < BK) sc[tid] += t;
        __syncthreads();
    }
    if (tid < BK) {
        int d = deg[tid];
        int pdeg = (d + 7) & ~7;
        int base = sc[tid] - pdeg;
        bas[tid] = base;
        int g = b * BK + tid;
        if (g < n) {
            dis[g] = rsqrtf((float)(d + 1));      // +1 self-loop
            rpde[g] = make_int2(clo + base, d);
        }
        for (int j = d; j < pdeg; j++)            // sentinel padding (<=7 per node)
            col[clo + base + j] = n;
    }
    __syncthreads();
    for (int i = tid; i < 8 * BK; i += 512)
        ((int*)wb)[i] += bas[i & (BK - 1)];       // wb[w][dl] += bas[dl]
    __syncthreads();
    for (int e = lo + w * 64 + lane; e < hi; e += 512) {
        unsigned r = recs[e];
        int dl = r & (BK - 1);
        int k = atomicAdd(&wb[w][dl], 1);         // wave-private cursor
        col[clo + k] = (int)(r >> BKSH);
    }
}

// ---------------- GEMM1 (MFMA bf16): h1s = bf16((x @ W1) * dis[row]); row n = zero sentinel ----------------

__global__ __launch_bounds__(256) void gemm1_k(const float* __restrict__ x,
                                               const float* __restrict__ W1,
                                               const float* __restrict__ dis,
                                               unsigned short* __restrict__ h1s, int n) {
    __shared__ unsigned short xb[64][136];   // +8 pad: rows 272B apart -> 2-way bank alias (free)
    __shared__ unsigned short wt[64][136];
    int tid = threadIdx.x;
    int r0b = blockIdx.x * 64;

    for (int c = tid; c < 2048; c += 256) {
        int k = c >> 4, n4 = (c & 15) * 4;
        float4 v = ((const float4*)W1)[c];
        wt[n4 + 0][k] = f2bf(v.x);
        wt[n4 + 1][k] = f2bf(v.y);
        wt[n4 + 2][k] = f2bf(v.z);
        wt[n4 + 3][k] = f2bf(v.w);
    }
    for (int c = tid; c < 2048; c += 256) {
        int r = c >> 5, k4 = (c & 31) * 4;
        int gr = r0b + r;
        float4 v = make_float4(0.f, 0.f, 0.f, 0.f);
        if (gr < n) v = ((const float4*)x)[(gr << 5) + (k4 >> 2)];
        ushort4 o;
        o.x = f2bf(v.x); o.y = f2bf(v.y); o.z = f2bf(v.z); o.w = f2bf(v.w);
        *(ushort4*)&xb[r][k4] = o;
    }
    __syncthreads();

    int w = tid >> 6, lane = tid & 63;
    int rr = lane & 15, q = lane >> 4;
    floatx4 acc0 = {0.f, 0.f, 0.f, 0.f}, acc1 = acc0, acc2 = acc0, acc3 = acc0;
    #pragma unroll
    for (int kt = 0; kt < 4; kt++) {
        int k0 = kt * 32 + q * 8;
        short8 a  = *(const short8*)&xb[w * 16 + rr][k0];
        short8 b0 = *(const short8*)&wt[rr][k0];
        short8 b1 = *(const short8*)&wt[16 + rr][k0];
        short8 b2 = *(const short8*)&wt[32 + rr][k0];
        short8 b3 = *(const short8*)&wt[48 + rr][k0];
        acc0 = __builtin_amdgcn_mfma_f32_16x16x32_bf16(a, b0, acc0, 0, 0, 0);
        acc1 = __builtin_amdgcn_mfma_f32_16x16x32_bf16(a, b1, acc1, 0, 0, 0);
        acc2 = __builtin_amdgcn_mfma_f32_16x16x32_bf16(a, b2, acc2, 0, 0, 0);
        acc3 = __builtin_amdgcn_mfma_f32_16x16x32_bf16(a, b3, acc3, 0, 0, 0);
    }
    #pragma unroll
    for (int t = 0; t < 4; t++) {
        int gr = r0b + w * 16 + q * 4 + t;
        if (gr < n) {
            float dd = dis[gr];
            unsigned short* o = &h1s[gr * 64];
            o[rr]      = f2bf(acc0[t] * dd);
            o[16 + rr] = f2bf(acc1[t] * dd);
            o[32 + rr] = f2bf(acc2[t] * dd);
            o[48 + rr] = f2bf(acc3[t] * dd);
        } else if (gr == n) {                    // sentinel zero row for padded gathers
            unsigned short* o = &h1s[gr * 64];
            o[rr] = 0; o[16 + rr] = 0; o[32 + rr] = 0; o[48 + rr] = 0;
        }
    }
}

// ---------------- Aggregation layer 1: TWO nodes per wave, issue-all-then-consume ----------------
// Per wave: 16 col loads + 16 row gathers + 2 self rows ALL issued before any consumption;
// sched_barrier(0) pins the schedule so the compiler cannot serialize to save VGPRs.
// Guards select sentinel n (zero row) by VALUE -- no exec divergence. Rare deg>32 via tail loops.

__global__ __launch_bounds__(256) void agg1_k(const unsigned* __restrict__ h1p,
                                              const int2* __restrict__ rpde,
                                              const int* __restrict__ col,
                                              unsigned* __restrict__ outp, int n) {
    int wv = (blockIdx.x * 256 + threadIdx.x) >> 6;
    int lane = threadIdx.x & 63;
    int nA = wv * 2;
    if (nA >= n) return;
    int nB = nA + 1;
    bool hasB = nB < n;
    int f2 = lane & 15, eslot = lane >> 4;
    const uint2* h1q = (const uint2*)h1p;

    int2 rdA = rpde[nA];
    int2 rdB = rpde[hasB ? nB : nA];
    int eA  = __builtin_amdgcn_readfirstlane(rdA.x);
    int dgA = __builtin_amdgcn_readfirstlane(rdA.y);
    int eB  = __builtin_amdgcn_readfirstlane(rdB.x);
    int dgB = hasB ? __builtin_amdgcn_readfirstlane(rdB.y) : 0;
    int pmA = ((dgA + 7) & ~7) - 1;
    int pmB = ((dgB + 7) & ~7) - 1;

    int i0 = eslot,      i1 = 4 + eslot,  i2 = 8 + eslot,  i3 = 12 + eslot;
    int i4 = 16 + eslot, i5 = 20 + eslot, i6 = 24 + eslot, i7 = 28 + eslot;

    // --- issue: 16 col loads ---
    int a0 = col[eA + min(i0, pmA)], a1 = col[eA + min(i1, pmA)];
    int a2 = col[eA + min(i2, pmA)], a3 = col[eA + min(i3, pmA)];
    int a4 = col[eA + min(i4, pmA)], a5 = col[eA + min(i5, pmA)];
    int a6 = col[eA + min(i6, pmA)], a7 = col[eA + min(i7, pmA)];
    int b0 = col[eB + min(i0, pmB)], b1 = col[eB + min(i1, pmB)];
    int b2 = col[eB + min(i2, pmB)], b3 = col[eB + min(i3, pmB)];
    int b4 = col[eB + min(i4, pmB)], b5 = col[eB + min(i5, pmB)];
    int b6 = col[eB + min(i6, pmB)], b7 = col[eB + min(i7, pmB)];
    a0 = (i0 <= pmA) ? a0 : n;  a1 = (i1 <= pmA) ? a1 : n;
    a2 = (i2 <= pmA) ? a2 : n;  a3 = (i3 <= pmA) ? a3 : n;
    a4 = (i4 <= pmA) ? a4 : n;  a5 = (i5 <= pmA) ? a5 : n;
    a6 = (i6 <= pmA) ? a6 : n;  a7 = (i7 <= pmA) ? a7 : n;
    b0 = (i0 <= pmB) ? b0 : n;  b1 = (i1 <= pmB) ? b1 : n;
    b2 = (i2 <= pmB) ? b2 : n;  b3 = (i3 <= pmB) ? b3 : n;
    b4 = (i4 <= pmB) ? b4 : n;  b5 = (i5 <= pmB) ? b5 : n;
    b6 = (i6 <= pmB) ? b6 : n;  b7 = (i7 <= pmB) ? b7 : n;
    // --- issue: 18 row gathers (2 nodes x 8 + 2 self) ---
    uint2 uA0 = h1q[a0 * 16 + f2], uA1 = h1q[a1 * 16 + f2];
    uint2 uA2 = h1q[a2 * 16 + f2], uA3 = h1q[a3 * 16 + f2];
    uint2 uA4 = h1q[a4 * 16 + f2], uA5 = h1q[a5 * 16 + f2];
    uint2 uA6 = h1q[a6 * 16 + f2], uA7 = h1q[a7 * 16 + f2];
    uint2 uB0 = h1q[b0 * 16 + f2], uB1 = h1q[b1 * 16 + f2];
    uint2 uB2 = h1q[b2 * 16 + f2], uB3 = h1q[b3 * 16 + f2];
    uint2 uB4 = h1q[b4 * 16 + f2], uB5 = h1q[b5 * 16 + f2];
    uint2 uB6 = h1q[b6 * 16 + f2], uB7 = h1q[b7 * 16 + f2];
    uint2 usA = h1q[nA * 16 + f2];
    uint2 usB = h1q[(hasB ? nB : n) * 16 + f2];
    __builtin_amdgcn_sched_barrier(0);   // nothing crosses: all loads in flight before consume

    float Alx = SUM8(LOX, uA0,uA1,uA2,uA3,uA4,uA5,uA6,uA7);
    float Ahx = SUM8(HIX, uA0,uA1,uA2,uA3,uA4,uA5,uA6,uA7);
    float Aly = SUM8(LOY, uA0,uA1,uA2,uA3,uA4,uA5,uA6,uA7);
    float Ahy = SUM8(HIY, uA0,uA1,uA2,uA3,uA4,uA5,uA6,uA7);
    float Blx = SUM8(LOX, uB0,uB1,uB2,uB3,uB4,uB5,uB6,uB7);
    float Bhx = SUM8(HIX, uB0,uB1,uB2,uB3,uB4,uB5,uB6,uB7);
    float Bly = SUM8(LOY, uB0,uB1,uB2,uB3,uB4,uB5,uB6,uB7);
    float Bhy = SUM8(HIY, uB0,uB1,uB2,uB3,uB4,uB5,uB6,uB7);

    if (pmA >= 32) {                      // rare tail (P ~ 1.5e-4)
        for (int b = 32; b <= pmA; b += 32) {
            int j0 = b+eslot, j1 = b+4+eslot, j2 = b+8+eslot, j3 = b+12+eslot;
            int j4 = b+16+eslot, j5 = b+20+eslot, j6 = b+24+eslot, j7 = b+28+eslot;
            int s0 = col[eA+min(j0,pmA)], s1 = col[eA+min(j1,pmA)];
            int s2 = col[eA+min(j2,pmA)], s3 = col[eA+min(j3,pmA)];
            int s4 = col[eA+min(j4,pmA)], s5 = col[eA+min(j5,pmA)];
            int s6 = col[eA+min(j6,pmA)], s7 = col[eA+min(j7,pmA)];
            s0=(j0<=pmA)?s0:n; s1=(j1<=pmA)?s1:n; s2=(j2<=pmA)?s2:n; s3=(j3<=pmA)?s3:n;
            s4=(j4<=pmA)?s4:n; s5=(j5<=pmA)?s5:n; s6=(j6<=pmA)?s6:n; s7=(j7<=pmA)?s7:n;
            uint2 v0=h1q[s0*16+f2], v1=h1q[s1*16+f2], v2=h1q[s2*16+f2], v3=h1q[s3*16+f2];
            uint2 v4=h1q[s4*16+f2], v5=h1q[s5*16+f2], v6=h1q[s6*16+f2], v7=h1q[s7*16+f2];
            Alx += SUM8(LOX, v0,v1,v2,v3,v4,v5,v6,v7);
            Ahx += SUM8(HIX, v0,v1,v2,v3,v4,v5,v6,v7);
            Aly += SUM8(LOY, v0,v1,v2,v3,v4,v5,v6,v7);
            Ahy += SUM8(HIY, v0,v1,v2,v3,v4,v5,v6,v7);
        }
    }
    if (pmB >= 32) {
        for (int b = 32; b <= pmB; b += 32) {
            int j0 = b+eslot, j1 = b+4+eslot, j2 = b+8+eslot, j3 = b+12+eslot;
            int j4 = b+16+eslot, j5 = b+20+eslot, j6 = b+24+eslot, j7 = b+28+eslot;
            int s0 = col[eB+min(j0,pmB)], s1 = col[eB+min(j1,pmB)];
            int s2 = col[eB+min(j2,pmB)], s3 = col[eB+min(j3,pmB)];
            int s4 = col[eB+min(j4,pmB)], s5 = col[eB+min(j5,pmB)];
            int s6 = col[eB+min(j6,pmB)], s7 = col[eB+min(j7,pmB)];
            s0=(j0<=pmB)?s0:n; s1=(j1<=pmB)?s1:n; s2=(j2<=pmB)?s2:n; s3=(j3<=pmB)?s3:n;
            s4=(j4<=pmB)?s4:n; s5=(j5<=pmB)?s5:n; s6=(j6<=pmB)?s6:n; s7=(j7<=pmB)?s7:n;
            uint2 v0=h1q[s0*16+f2], v1=h1q[s1*16+f2], v2=h1q[s2*16+f2], v3=h1q[s3*16+f2];
            uint2 v4=h1q[s4*16+f2], v5=h1q[s5*16+f2], v6=h1q[s6*16+f2], v7=h1q[s7*16+f2];
            Blx += SUM8(LOX, v0,v1,v2,v3,v4,v5,v6,v7);
            Bhx += SUM8(HIX, v0,v1,v2,v3,v4,v5,v6,v7);
            Bly += SUM8(LOY, v0,v1,v2,v3,v4,v5,v6,v7);
            Bhy += SUM8(HIY, v0,v1,v2,v3,v4,v5,v6,v7);
        }
    }

    Alx += __shfl_xor(Alx, 16, 64); Alx += __shfl_xor(Alx, 32, 64);
    Ahx += __shfl_xor(Ahx, 16, 64); Ahx += __shfl_xor(Ahx, 32, 64);
    Aly += __shfl_xor(Aly, 16, 64); Aly += __shfl_xor(Aly, 32, 64);
    Ahy += __shfl_xor(Ahy, 16, 64); Ahy += __shfl_xor(Ahy, 32, 64);
    Blx += __shfl_xor(Blx, 16, 64); Blx += __shfl_xor(Blx, 32, 64);
    Bhx += __shfl_xor(Bhx, 16, 64); Bhx += __shfl_xor(Bhx, 32, 64);
    Bly += __shfl_xor(Bly, 16, 64); Bly += __shfl_xor(Bly, 32, 64);
    Bhy += __shfl_xor(Bhy, 16, 64); Bhy += __shfl_xor(Bhy, 32, 64);

    if (eslot == 0) {
        float dnA = rsqrtf((float)(dgA + 1));
        uint2 o;
        o.x = pack2bf((Alx + lo_f(usA.x)) * dnA, (Ahx + hi_f(usA.x)) * dnA);
        o.y = pack2bf((Aly + lo_f(usA.y)) * dnA, (Ahy + hi_f(usA.y)) * dnA);
        ((uint2*)outp)[nA * 16 + f2] = o;
        if (hasB) {
            float dnB = rsqrtf((float)(dgB + 1));
            o.x = pack2bf((Blx + lo_f(usB.x)) * dnB, (Bhx + hi_f(usB.x)) * dnB);
            o.y = pack2bf((Bly + lo_f(usB.y)) * dnB, (Bhy + hi_f(usB.y)) * dnB);
            ((uint2*)outp)[nB * 16 + f2] = o;
        }
    }
}

// ---------------- BN stats (bf16 input) ----------------

__global__ __launch_bounds__(256) void bnstats_k(const unsigned short* __restrict__ agg1b,
                                                 float* __restrict__ stats, int n) {
    int f = threadIdx.x & 63, g = threadIdx.x >> 6;
    float sum = 0.f, sq = 0.f;
    for (int r = blockIdx.x * 4 + g; r < n; r += gridDim.x * 4) {
        float v = bf2f(agg1b[r * 64 + f]);
        sum += v; sq += v * v;
    }
    __shared__ float s1[4][64], s2[4][64];
    s1[g][f] = sum; s2[g][f] = sq;
    __syncthreads();
    if (g == 0) {
        sum = s1[0][f] + s1[1][f] + s1[2][f] + s1[3][f];
        sq  = s2[0][f] + s2[1][f] + s2[2][f] + s2[3][f];
        atomicAdd(&stats[f], sum);
        atomicAdd(&stats[64 + f], sq);
    }
}

// ---------------- GEMM2 (MFMA bf16), BN fold inlined: h2s = bf16((relu(agg1b*s+t) @ W2) * dis[row]) ----------------

__global__ __launch_bounds__(256) void gemm2_k(const unsigned short* __restrict__ agg1b,
                                               const float* __restrict__ W2,
                                               const float* __restrict__ stats,
                                               const float* __restrict__ gamma, const float* __restrict__ beta,
                                               const float* __restrict__ dis,
                                               unsigned short* __restrict__ h2s, float invn, int n) {
    __shared__ unsigned short ab[64][72];    // +8 pad
    __shared__ unsigned short wt[32][72];
    __shared__ float s_s[64], s_t[64];
    int tid = threadIdx.x;
    int r0b = blockIdx.x * 64;
    if (tid < 64) {                          // BN fold (b1 cancels by shift invariance)
        float mean = stats[tid] * invn;
        float var = stats[64 + tid] * invn - mean * mean;
        float s = gamma[tid] * rsqrtf(var + BN_EPS);
        s_s[tid] = s;
        s_t[tid] = beta[tid] - mean * s;
    }
    for (int c = tid; c < 512; c += 256) {   // stage W2^T (512 float4)
        int k = c >> 3, n4 = (c & 7) * 4;
        float4 v = ((const float4*)W2)[c];
        wt[n4 + 0][k] = f2bf(v.x);
        wt[n4 + 1][k] = f2bf(v.y);
        wt[n4 + 2][k] = f2bf(v.z);
        wt[n4 + 3][k] = f2bf(v.w);
    }
    __syncthreads();
    for (int c = tid; c < 512; c += 256) {
        int r = c >> 3, k0 = (c & 7) * 8;
        int gr = r0b + r;
        unsigned short tmp[8];
        if (gr < n) {
            const unsigned short* ap = &agg1b[gr * 64 + k0];
            #pragma unroll
            for (int j = 0; j < 8; j++)
                tmp[j] = f2bf(fmaxf(bf2f(ap[j]) * s_s[k0 + j] + s_t[k0 + j], 0.f));
        } else {
            #pragma unroll
            for (int j = 0; j < 8; j++) tmp[j] = 0;
        }
        *(short8*)&ab[r][k0] = *(short8*)tmp;
    }
    __syncthreads();

    int w = tid >> 6, lane = tid & 63;
    int rr = lane & 15, q = lane >> 4;
    floatx4 acc0 = {0.f, 0.f, 0.f, 0.f}, acc1 = acc0;
    #pragma unroll
    for (int kt = 0; kt < 2; kt++) {
        int k0 = kt * 32 + q * 8;
        short8 a  = *(const short8*)&ab[w * 16 + rr][k0];
        short8 b0 = *(const short8*)&wt[rr][k0];
        short8 b1 = *(const short8*)&wt[16 + rr][k0];
        acc0 = __builtin_amdgcn_mfma_f32_16x16x32_bf16(a, b0, acc0, 0, 0, 0);
        acc1 = __builtin_amdgcn_mfma_f32_16x16x32_bf16(a, b1, acc1, 0, 0, 0);
    }
    #pragma unroll
    for (int t = 0; t < 4; t++) {
        int gr = r0b + w * 16 + q * 4 + t;
        if (gr < n) {
            float dd = dis[gr];
            h2s[gr * 32 + rr]      = f2bf(acc0[t] * dd);
            h2s[gr * 32 + 16 + rr] = f2bf(acc1[t] * dd);
        } else if (gr == n) {                // sentinel zero row for padded gathers
            h2s[gr * 32 + rr]      = 0;
            h2s[gr * 32 + 16 + rr] = 0;
        }
    }
}

// ---------------- Aggregation layer 2: TWO nodes per half-wave (4/wave), issue-all-then-consume ----------------

__global__ __launch_bounds__(256) void agg2_k(const unsigned* __restrict__ h2p,
                                              const int2* __restrict__ rpde,
                                              const int* __restrict__ col, const float* __restrict__ b2,
                                              float* __restrict__ out, int n) {
    int wv = (blockIdx.x * 256 + threadIdx.x) >> 6;
    int lane = threadIdx.x & 63;
    int half = lane >> 5, hl = lane & 31;
    int nA = wv * 4 + half * 2;
    if (nA >= n) return;
    int nB = nA + 1;
    bool hasB = nB < n;
    int f2 = hl & 7, eslot = hl >> 3;        // uint2 column of 8-uint2 row; eslot in [0,4)
    const uint2* h2q = (const uint2*)h2p;    // 8 uint2 per row

    int2 rdA = rpde[nA];                     // uniform within half
    int2 rdB = rpde[hasB ? nB : nA];
    int eA = rdA.x, dgA = rdA.y;
    int eB = rdB.x, dgB = hasB ? rdB.y : 0;
    int pmA = ((dgA + 7) & ~7) - 1;
    int pmB = ((dgB + 7) & ~7) - 1;

    int i0 = eslot,      i1 = 4 + eslot,  i2 = 8 + eslot,  i3 = 12 + eslot;
    int i4 = 16 + eslot, i5 = 20 + eslot, i6 = 24 + eslot, i7 = 28 + eslot;

    int a0 = col[eA + min(i0, pmA)], a1 = col[eA + min(i1, pmA)];
    int a2 = col[eA + min(i2, pmA)], a3 = col[eA + min(i3, pmA)];
    int a4 = col[eA + min(i4, pmA)], a5 = col[eA + min(i5, pmA)];
    int a6 = col[eA + min(i6, pmA)], a7 = col[eA + min(i7, pmA)];
    int b0 = col[eB + min(i0, pmB)], b1 = col[eB + min(i1, pmB)];
    int b2i = col[eB + min(i2, pmB)], b3 = col[eB + min(i3, pmB)];
    int b4 = col[eB + min(i4, pmB)], b5 = col[eB + min(i5, pmB)];
    int b6 = col[eB + min(i6, pmB)], b7 = col[eB + min(i7, pmB)];
    a0 = (i0 <= pmA) ? a0 : n;  a1 = (i1 <= pmA) ? a1 : n;
    a2 = (i2 <= pmA) ? a2 : n;  a3 = (i3 <= pmA) ? a3 : n;
    a4 = (i4 <= pmA) ? a4 : n;  a5 = (i5 <= pmA) ? a5 : n;
    a6 = (i6 <= pmA) ? a6 : n;  a7 = (i7 <= pmA) ? a7 : n;
    b0 = (i0 <= pmB) ? b0 : n;  b1 = (i1 <= pmB) ? b1 : n;
    b2i = (i2 <= pmB) ? b2i : n; b3 = (i3 <= pmB) ? b3 : n;
    b4 = (i4 <= pmB) ? b4 : n;  b5 = (i5 <= pmB) ? b5 : n;
    b6 = (i6 <= pmB) ? b6 : n;  b7 = (i7 <= pmB) ? b7 : n;
    uint2 uA0 = h2q[a0 * 8 + f2], uA1 = h2q[a1 * 8 + f2];
    uint2 uA2 = h2q[a2 * 8 + f2], uA3 = h2q[a3 * 8 + f2];
    uint2 uA4 = h2q[a4 * 8 + f2], uA5 = h2q[a5 * 8 + f2];
    uint2 uA6 = h2q[a6 * 8 + f2], uA7 = h2q[a7 * 8 + f2];
    uint2 uB0 = h2q[b0 * 8 + f2], uB1 = h2q[b1 * 8 + f2];
    uint2 uB2 = h2q[b2i * 8 + f2], uB3 = h2q[b3 * 8 + f2];
    uint2 uB4 = h2q[b4 * 8 + f2], uB5 = h2q[b5 * 8 + f2];
    uint2 uB6 = h2q[b6 * 8 + f2], uB7 = h2q[b7 * 8 + f2];
    uint2 usA = h2q[nA * 8 + f2];
    uint2 usB = h2q[(hasB ? nB : n) * 8 + f2];
    __builtin_amdgcn_sched_barrier(0);

    float Alx = SUM8(LOX, uA0,uA1,uA2,uA3,uA4,uA5,uA6,uA7);
    float Ahx = SUM8(HIX, uA0,uA1,uA2,uA3,uA4,uA5,uA6,uA7);
    float Aly = SUM8(LOY, uA0,uA1,uA2,uA3,uA4,uA5,uA6,uA7);
    float Ahy = SUM8(HIY, uA0,uA1,uA2,uA3,uA4,uA5,uA6,uA7);
    float Blx = SUM8(LOX, uB0,uB1,uB2,uB3,uB4,uB5,uB6,uB7);
    float Bhx = SUM8(HIX, uB0,uB1,uB2,uB3,uB4,uB5,uB6,uB7);
    float Bly = SUM8(LOY, uB0,uB1,uB2,uB3,uB4,uB5,uB6,uB7);
    float Bhy = SUM8(HIY, uB0,uB1,uB2,uB3,uB4,uB5,uB6,uB7);

    if (pmA >= 32) {
        for (int b = 32; b <= pmA; b += 32) {
            int j0=b+eslot, j1=b+4+eslot, j2=b+8+eslot, j3=b+12+eslot;
            int j4=b+16+eslot, j5=b+20+eslot, j6=b+24+eslot, j7=b+28+eslot;
            int s0=col[eA+min(j0,pmA)], s1=col[eA+min(j1,pmA)];
            int s2=col[eA+min(j2,pmA)], s3=col[eA+min(j3,pmA)];
            int s4=col[eA+min(j4,pmA)], s5=col[eA+min(j5,pmA)];
            int s6=col[eA+min(j6,pmA)], s7=col[eA+min(j7,pmA)];
            s0=(j0<=pmA)?s0:n; s1=(j1<=pmA)?s1:n; s2=(j2<=pmA)?s2:n; s3=(j3<=pmA)?s3:n;
            s4=(j4<=pmA)?s4:n; s5=(j5<=pmA)?s5:n; s6=(j6<=pmA)?s6:n; s7=(j7<=pmA)?s7:n;
            uint2 v0=h2q[s0*8+f2], v1=h2q[s1*8+f2], v2=h2q[s2*8+f2], v3=h2q[s3*8+f2];
            uint2 v4=h2q[s4*8+f2], v5=h2q[s5*8+f2], v6=h2q[s6*8+f2], v7=h2q[s7*8+f2];
            Alx += SUM8(LOX, v0,v1,v2,v3,v4,v5,v6,v7);
            Ahx += SUM8(HIX, v0,v1,v2,v3,v4,v5,v6,v7);
            Aly += SUM8(LOY, v0,v1,v2,v3,v4,v5,v6,v7);
            Ahy += SUM8(HIY, v0,v1,v2,v3,v4,v5,v6,v7);
        }
    }
    if (pmB >= 32) {
        for (int b = 32; b <= pmB; b += 32) {
            int j0=b+eslot, j1=b+4+eslot, j2=b+8+eslot, j3=b+12+eslot;
            int j4=b+16+eslot, j5=b+20+eslot, j6=b+24+eslot, j7=b+28+eslot;
            int s0=col[eB+min(j0,pmB)], s1=col[eB+min(j1,pmB)];
            int s2=col[eB+min(j2,pmB)], s3=col[eB+min(j3,pmB)];
            int s4=col[eB+min(j4,pmB)], s5=col[eB+min(j5,pmB)];
            int s6=col[eB+min(j6,pmB)], s7=col[eB+min(j7,pmB)];
            s0=(j0<=pmB)?s0:n; s1=(j1<=pmB)?s1:n; s2=(j2<=pmB)?s2:n; s3=(j3<=pmB)?s3:n;
            s4=(j4<=pmB)?s4:n; s5=(j5<=pmB)?s5:n; s6=(j6<=pmB)?s6:n; s7=(j7<=pmB)?s7:n;
            uint2 v0=h2q[s0*8+f2], v1=h2q[s1*8+f2], v2=h2q[s2*8+f2], v3=h2q[s3*8+f2];
            uint2 v4=h2q[s4*8+f2], v5=h2q[s5*8+f2], v6=h2q[s6*8+f2], v7=h2q[s7*8+f2];
            Blx += SUM8(LOX, v0,v1,v2,v3,v4,v5,v6,v7);
            Bhx += SUM8(HIX, v0,v1,v2,v3,v4,v5,v6,v7);
            Bly += SUM8(LOY, v0,v1,v2,v3,v4,v5,v6,v7);
            Bhy += SUM8(HIY, v0,v1,v2,v3,v4,v5,v6,v7);
        }
    }

    Alx += __shfl_xor(Alx, 8, 64); Alx += __shfl_xor(Alx, 16, 64);
    Ahx += __shfl_xor(Ahx, 8, 64); Ahx += __shfl_xor(Ahx, 16, 64);
    Aly += __shfl_xor(Aly, 8, 64); Aly += __shfl_xor(Aly, 16, 64);
    Ahy += __shfl_xor(Ahy, 8, 64); Ahy += __shfl_xor(Ahy, 16, 64);
    Blx += __shfl_xor(Blx, 8, 64); Blx += __shfl_xor(Blx, 16, 64);
    Bhx += __shfl_xor(Bhx, 8, 64); Bhx += __shfl_xor(Bhx, 16, 64);
    Bly += __shfl_xor(Bly, 8, 64); Bly += __shfl_xor(Bly, 16, 64);
    Bhy += __shfl_xor(Bhy, 8, 64); Bhy += __shfl_xor(Bhy, 16, 64);

    if (eslot == 0) {
        float dnA = rsqrtf((float)(dgA + 1));
        float4 bb = ((const float4*)b2)[f2];
        float4 o;
        o.x = (Alx + lo_f(usA.x)) * dnA + bb.x;
        o.y = (Ahx + hi_f(usA.x)) * dnA + bb.y;
        o.z = (Aly + lo_f(usA.y)) * dnA + bb.z;
        o.w = (Ahy + hi_f(usA.y)) * dnA + bb.w;
        ((float4*)out)[nA * 8 + f2] = o;
        if (hasB) {
            float dnB = rsqrtf((float)(dgB + 1));
            o.x = (Blx + lo_f(usB.x)) * dnB + bb.x;
            o.y = (Bhx + hi_f(usB.x)) * dnB + bb.y;
            o.z = (Bly + lo_f(usB.y)) * dnB + bb.z;
            o.w = (Bhy + hi_f(usB.y)) * dnB + bb.w;
            ((float4*)out)[nB * 8 + f2] = o;
        }
    }
}

// ---------------- launch ----------------

extern "C" void kernel_launch(void* const* d_in, const int* in_sizes, int n_in,
                              void* d_out, int out_size, void* d_ws, size_t ws_size,
                              hipStream_t stream) {
    const float* x      = (const float*)d_in[0];
    const int*   ei     = (const int*)d_in[1];
    const float* W1     = (const float*)d_in[2];
    // d_in[3] = b1 (cancels inside BN)
    const float* gamma1 = (const float*)d_in[4];
    const float* beta1  = (const float*)d_in[5];
    const float* W2     = (const float*)d_in[6];
    const float* b2     = (const float*)d_in[7];
    float* out = (float*)d_out;

    int N = in_sizes[0] / DIN;
    int E = in_sizes[1] / 2;
    const int* src = ei;
    const int* dst = ei + E;
    int nbk = (N + BK - 1) >> BKSH;         // 782
    int chunk = (E + G - 1) / G;

    size_t off = 0;  // 4B units
    auto alloc = [&](size_t elems) -> void* {
        void* p = (char*)d_ws + off * 4;
        off += (elems + 127) & ~size_t(127);
        return p;
    };
    int*            hist_g = (int*)alloc((size_t)G * NBK_MAX);
    int*            rowoff = (int*)alloc((size_t)G * NBK_MAX);            // g-major [G][nbk]
    int*            tot    = (int*)alloc(NBK_MAX);
    unsigned*       recs   = (unsigned*)alloc((size_t)NBK_MAX * CAP);     // fixed-CAP regions
    int*            col    = (int*)alloc((size_t)NBK_MAX * CCAP);         // padded-to-8 CSR cols
    float*          dis    = (float*)alloc(N);
    int2*           rpde   = (int2*)alloc((size_t)N * 2);
    float*          stats  = (float*)alloc(128);
    unsigned short* h1s    = (unsigned short*)alloc((size_t)(N + 1) * DH / 2);  // bf16, +1 sentinel row
    unsigned short* agg1b  = (unsigned short*)alloc((size_t)N * DH / 2);        // bf16
    unsigned short* h2s    = h1s;  // h1s dead after agg1_k; row N (32 bf16) fits inside region

    hipMemsetAsync(stats, 0, 128 * sizeof(float), stream);

    hist_k<<<G, 512, 0, stream>>>(dst, hist_g, E, nbk, chunk);
    scan_k<<<(nbk + 15) / 16, 256, 0, stream>>>(hist_g, rowoff, tot, nbk);
    scatter_k<<<G, 512, 0, stream>>>(src, dst, rowoff, recs, E, nbk, chunk);
    csr_k<<<nbk, 512, 0, stream>>>(recs, tot, dis, rpde, col, N);

    gemm1_k<<<(N + 63) / 64, 256, 0, stream>>>(x, W1, dis, h1s, N);
    agg1_k<<<(N + 7) / 8, 256, 0, stream>>>((const unsigned*)h1s, rpde, col, (unsigned*)agg1b, N);

    bnstats_k<<<400, 256, 0, stream>>>(agg1b, stats, N);

    gemm2_k<<<(N + 63) / 64, 256, 0, stream>>>(agg1b, W2, stats, gamma1, beta1, dis, h2s,
                                               1.0f / (float)N, N);
    agg2_k<<<(N + 15) / 16, 256, 0, stream>>>((const unsigned*)h2s, rpde, col, b2, out, N);
}